// Round 2
// baseline (735.663 us; speedup 1.0000x reference)
//
#include <hip/hip_runtime.h>
#include <hip/hip_bf16.h>

// Problem constants
#define BDIM 4
#define SDIM 2048
#define MDIM 4
#define DDIM 2048
#define EDIM 1024
#define NTOK 8192           // B*S
#define NGEMM 10240         // D + M*D  (value cols + keys cols)
#define KDIM 1024           // E
#define EPS_GATE 1.1920929e-07f
#define EPS_CONV 1e-5f
#define RSQRT_D 0.022097086912079608f   // 1/sqrt(2048)

typedef __bf16 bf16x8 __attribute__((ext_vector_type(8)));
typedef float f32x4 __attribute__((ext_vector_type(4)));

__constant__ int OFFS[8] = {0, 130003, 260024, 390051, 520094, 650145, 780202, 910271};

__device__ __forceinline__ float bf2f(unsigned short u) {
  union { unsigned int i; float f; } x; x.i = ((unsigned int)u) << 16; return x.f;
}
__device__ __forceinline__ unsigned short f2bf(float f) {
  __hip_bfloat16 h = __float2bfloat16(f);
  unsigned short u; __builtin_memcpy(&u, &h, 2); return u;
}

// ---------------- zero accumulators ------------------------------------------
__global__ __launch_bounds__(256) void k_zero(float* __restrict__ p, int n) {
  const int i = blockIdx.x * 256 + threadIdx.x;
  if (i < n) p[i] = 0.f;
}

// ---------------- gather: emb_table rows -> bf16 emb [8192][1024] ------------
__global__ __launch_bounds__(256) void k_gather(const int* __restrict__ idx,
                                                const float* __restrict__ table,
                                                unsigned short* __restrict__ embb) {
  const int tok = blockIdx.x;
  const int tid = threadIdx.x;
  const int h = tid >> 5;            // 8 heads x 32 threads
  const int e = (tid & 31) * 4;      // 4 floats per thread
  const int row = idx[tok * 8 + h] + OFFS[h];
  const float4 v = *(const float4*)(table + (size_t)row * 128 + e);
  ushort4 st;
  st.x = f2bf(v.x); st.y = f2bf(v.y); st.z = f2bf(v.z); st.w = f2bf(v.w);
  *(ushort4*)(embb + (size_t)tok * 1024 + h * 128 + e) = st;
}

// ---------------- weight convert: [w_v ; w_k] fp32 -> bf16 [10240][1024] -----
__global__ __launch_bounds__(256) void k_cvtw(const float* __restrict__ wv,
                                              const float* __restrict__ wk,
                                              unsigned short* __restrict__ Wb) {
  const size_t i = ((size_t)blockIdx.x * 256 + threadIdx.x) * 4;
  const size_t NV = (size_t)DDIM * EDIM;  // 2097152
  float4 v;
  if (i < NV) v = *(const float4*)(wv + i);
  else        v = *(const float4*)(wk + (i - NV));
  ushort4 st;
  st.x = f2bf(v.x); st.y = f2bf(v.y); st.z = f2bf(v.z); st.w = f2bf(v.w);
  *(ushort4*)(Wb + i) = st;
}

// ---------------- GEMM: C[8192,10240] = emb[8192,1024] * W^T -----------------
// m97 structure: 128x128 tile, BK=64, global_load_lds(16B), mfma 16x16x32 bf16.
// Value cols (<2048): store fp32 + accumulate msv = sum(v^2) per token.
// Key cols (>=2048): never materialized — reduce sk=sum(k^2), sd=sum(k*h*wk*wh),
// sh=sum(h^2) per (token, m) via shuffle-reduce + atomicAdd.
#define GLDS(g, l) __builtin_amdgcn_global_load_lds(                        \
    (const __attribute__((address_space(1))) void*)(g),                    \
    (__attribute__((address_space(3))) void*)(l), 16, 0, 0)

__global__ __launch_bounds__(256) void k_gemm(const unsigned short* __restrict__ A,
                                              const unsigned short* __restrict__ Bw,
                                              const float* __restrict__ hidden,
                                              const float* __restrict__ norm_h,
                                              const float* __restrict__ norm_k,
                                              float* __restrict__ Cv,      // [8192][2048]
                                              float* __restrict__ sk,
                                              float* __restrict__ sd,
                                              float* __restrict__ sh,
                                              float* __restrict__ msv)
{
  __shared__ __align__(16) unsigned short lA[128 * 64];
  __shared__ __align__(16) unsigned short lB[128 * 64];
  const int tid = threadIdx.x;
  const int lane = tid & 63, wave = tid >> 6;
  const int row0 = blockIdx.y * 128;
  const int col0 = blockIdx.x * 128;
  const int wr = (wave >> 1) * 64, wc = (wave & 1) * 64;

  f32x4 acc[4][4] = {};

  for (int k0 = 0; k0 < KDIM; k0 += 64) {
#pragma unroll
    for (int it = 0; it < 4; ++it) {
      const int sg = wave * 4 + it;          // 16 segments of 1024B per tile
      const int chunk = sg * 64 + lane;      // 16B chunk index
      const int r = chunk >> 3;              // tile row (8 chunks per 128B row)
      const int c = (chunk & 7) * 8;         // bf16 col
      GLDS(A  + (size_t)(row0 + r) * KDIM + k0 + c, (char*)lA + sg * 1024);
      GLDS(Bw + (size_t)(col0 + r) * KDIM + k0 + c, (char*)lB + sg * 1024);
    }
    __syncthreads();
    const int lr = lane & 15;
#pragma unroll
    for (int kk = 0; kk < 2; ++kk) {
      const int lk = kk * 32 + (lane >> 4) * 8;
      bf16x8 af[4], bfr[4];
#pragma unroll
      for (int i = 0; i < 4; ++i)
        af[i] = *(const bf16x8*)(lA + (wr + i * 16 + lr) * 64 + lk);
#pragma unroll
      for (int i = 0; i < 4; ++i)
        bfr[i] = *(const bf16x8*)(lB + (wc + i * 16 + lr) * 64 + lk);
#pragma unroll
      for (int i = 0; i < 4; ++i)
#pragma unroll
        for (int j = 0; j < 4; ++j)
          acc[i][j] = __builtin_amdgcn_mfma_f32_16x16x32_bf16(af[i], bfr[j], acc[i][j], 0, 0, 0);
    }
    __syncthreads();
  }

  // epilogue: C/D layout col=lane&15, row=(lane>>4)*4+reg  [verified m89/m91]
  const int lcol = lane & 15;
  const int rbase = (lane >> 4) * 4;

  if (col0 < DDIM) {
    // ---- value block: store fp32 rows + msv partials ----
#pragma unroll
    for (int i = 0; i < 4; ++i) {
#pragma unroll
      for (int j = 0; j < 4; ++j) {
        const int gr = row0 + wr + i * 16 + rbase;
        const int gc = col0 + wc + j * 16 + lcol;
        float* p = Cv + (size_t)gr * DDIM + gc;
#pragma unroll
        for (int r = 0; r < 4; ++r) p[(size_t)r * DDIM] = acc[i][j][r];
      }
    }
#pragma unroll
    for (int i = 0; i < 4; ++i) {
#pragma unroll
      for (int r = 0; r < 4; ++r) {
        float pv = 0.f;
#pragma unroll
        for (int j = 0; j < 4; ++j) { const float v = acc[i][j][r]; pv += v * v; }
#pragma unroll
        for (int off = 1; off < 16; off <<= 1) pv += __shfl_xor(pv, off);
        if (lcol == 0) atomicAdd(&msv[row0 + wr + i * 16 + rbase + r], pv);
      }
    }
  } else {
    // ---- key block: fused score reductions, keys never hit memory ----
    const int m = (col0 - DDIM) >> 11;                 // block fully inside one m
    const int dbase = ((col0 - DDIM) & (DDIM - 1)) + wc;
#pragma unroll
    for (int i = 0; i < 4; ++i) {
#pragma unroll
      for (int r = 0; r < 4; ++r) {
        const int grow = row0 + wr + i * 16 + rbase + r;
        float psk = 0.f, psd = 0.f, psh = 0.f;
#pragma unroll
        for (int j = 0; j < 4; ++j) {
          const int d = dbase + j * 16 + lcol;
          const float kv = acc[i][j][r];
          const float hv = hidden[((size_t)grow * 4 + m) * DDIM + d];
          const float wt = norm_k[m * DDIM + d] * norm_h[m * DDIM + d];
          psk += kv * kv;
          psh += hv * hv;
          psd += kv * hv * wt;
        }
#pragma unroll
        for (int off = 1; off < 16; off <<= 1) {
          psk += __shfl_xor(psk, off);
          psd += __shfl_xor(psd, off);
          psh += __shfl_xor(psh, off);
        }
        if (lcol == 0) {
          atomicAdd(&sk[grow * 4 + m], psk);
          atomicAdd(&sd[grow * 4 + m], psd);
          atomicAdd(&sh[grow * 4 + m], psh);
        }
      }
    }
  }
}

// ---------------- finalize: 32768 scalars -> gates, alphas -------------------
__global__ __launch_bounds__(256) void k_finalize(const float* __restrict__ sk,
                                                  const float* __restrict__ sd,
                                                  const float* __restrict__ sh,
                                                  const float* __restrict__ msvb,
                                                  float* __restrict__ gates,
                                                  float* __restrict__ alphas) {
  const int idx = blockIdx.x * 256 + threadIdx.x;   // tok*4 + m
  const int tok = idx >> 2;
  const float msk = sk[idx] * (1.f / 2048.f) + EPS_GATE;
  const float msh = sh[idx] * (1.f / 2048.f) + EPS_GATE;
  const float score = sd[idx] * rsqrtf(msk) * rsqrtf(msh) * RSQRT_D;
  const float sgn = (score > 0.f) ? 1.f : ((score < 0.f) ? -1.f : 0.f);
  const float g = sqrtf(fmaxf(fabsf(score), 1e-6f)) * sgn;
  const float gate = 1.f / (1.f + expf(-g));
  const float msv = msvb[tok] * (1.f / 2048.f);
  gates[idx] = gate;
  alphas[idx] = gate * rsqrtf(gate * gate * msv + EPS_CONV);
}

// ---------------- final: one thread owns (tok, d), loops m -------------------
// out[tok,m,d] = hidden + gate*v + silu(wcn * sum_j cw[:,3-j]*alpha_j*v(tok-3j))
__global__ __launch_bounds__(256) void k_final(const float* __restrict__ hidden,
                                               const float* __restrict__ value,
                                               const float* __restrict__ gates,
                                               const float* __restrict__ alphas,
                                               const float* __restrict__ wcn,
                                               const float* __restrict__ cw,   // [M*D][4]
                                               float* __restrict__ outp) {
  const long lin = (long)blockIdx.x * 256 + threadIdx.x;  // (tok, d4)
  const int d4 = (int)(lin & 511);
  const int tok = (int)(lin >> 9);
  const int s = tok & (SDIM - 1);
  const int d = d4 * 4;

  // conv taps: shared across all 4 branches (this is the 4x L3-traffic fix)
  float4 vj[4];
  vj[0] = *(const float4*)(value + (size_t)tok * DDIM + d);
#pragma unroll
  for (int j = 1; j < 4; ++j) {
    if (s >= 3 * j) vj[j] = *(const float4*)(value + (size_t)(tok - 3 * j) * DDIM + d);
    else            vj[j] = make_float4(0.f, 0.f, 0.f, 0.f);
  }

#pragma unroll
  for (int m = 0; m < 4; ++m) {
    const float g = gates[tok * 4 + m];
    const float4 h4 = *(const float4*)(hidden + ((size_t)tok * 4 + m) * DDIM + d);
    const float4 wn = *(const float4*)(wcn + m * DDIM + d);
    float a[4];
#pragma unroll
    for (int j = 0; j < 4; ++j)
      a[j] = (s >= 3 * j) ? alphas[(tok - 3 * j) * 4 + m] : 0.f;
    float cwr[4][4];
#pragma unroll
    for (int i = 0; i < 4; ++i)
      *(float4*)cwr[i] = *(const float4*)(cw + (size_t)(m * DDIM + d + i) * 4);

    float cx = 0.f, cy = 0.f, cz = 0.f, cv = 0.f;
#pragma unroll
    for (int j = 0; j < 4; ++j) {
      const int t = 3 - j;
      const float aj = a[j];
      cx += cwr[0][t] * aj * vj[j].x;
      cy += cwr[1][t] * aj * vj[j].y;
      cz += cwr[2][t] * aj * vj[j].z;
      cv += cwr[3][t] * aj * vj[j].w;
    }
    cx *= wn.x; cy *= wn.y; cz *= wn.z; cv *= wn.w;
    cx = cx / (1.f + expf(-cx));
    cy = cy / (1.f + expf(-cy));
    cz = cz / (1.f + expf(-cz));
    cv = cv / (1.f + expf(-cv));

    float4 o;
    o.x = h4.x + g * vj[0].x + cx;
    o.y = h4.y + g * vj[0].y + cy;
    o.z = h4.z + g * vj[0].z + cz;
    o.w = h4.w + g * vj[0].w + cv;
    *(float4*)(outp + ((size_t)tok * 4 + m) * DDIM + d) = o;
  }
}

// ---------------- launcher ---------------------------------------------------
extern "C" void kernel_launch(void* const* d_in, const int* in_sizes, int n_in,
                              void* d_out, int out_size, void* d_ws, size_t ws_size,
                              hipStream_t stream) {
  const int*   hash_idx = (const int*)d_in[0];
  const float* hidden   = (const float*)d_in[1];
  const float* table    = (const float*)d_in[2];
  const float* w_v      = (const float*)d_in[3];
  const float* w_k      = (const float*)d_in[4];
  const float* norm_h   = (const float*)d_in[5];
  const float* norm_k   = (const float*)d_in[6];
  const float* wcn      = (const float*)d_in[7];
  const float* cw       = (const float*)d_in[8];
  float* outp = (float*)d_out;
  char* ws = (char*)d_ws;

  // workspace layout (bytes)
  unsigned short* embb  = (unsigned short*)(ws + 0);          // 16,777,216
  unsigned short* Wb    = (unsigned short*)(ws + 16777216);   // 20,971,520
  float*          value = (float*)(ws + 37748736);            // 67,108,864
  float*          sk    = (float*)(ws + 104857600);           // 131,072
  float*          sd    = (float*)(ws + 104988672);           // 131,072
  float*          sh    = (float*)(ws + 105119744);           // 131,072
  float*          msv   = (float*)(ws + 105250816);           // 32,768
  float*          gates = (float*)(ws + 105283584);           // 131,072
  float*          alphas= (float*)(ws + 105414656);           // 131,072 (end ~100.7 MB)

  // zero the atomic accumulators every call (harness does not re-poison)
  const int nzero = (4 * 32768 + 8192);   // sk+sd+sh (3*32768) + msv... = 106496+ pad
  k_zero<<<(139264 + 255) / 256, 256, 0, stream>>>(sk, 3 * 32768 + 8192);
  (void)nzero;

  k_gather<<<NTOK, 256, 0, stream>>>(hash_idx, table, embb);
  k_cvtw<<<10240, 256, 0, stream>>>(w_v, w_k, Wb);
  dim3 gg(NGEMM / 128, NTOK / 128);  // (80, 64)
  k_gemm<<<gg, 256, 0, stream>>>(embb, Wb, hidden, norm_h, norm_k,
                                 value, sk, sd, sh, msv);
  k_finalize<<<NTOK * MDIM / 256, 256, 0, stream>>>(sk, sd, sh, msv, gates, alphas);
  k_final<<<(NTOK * DDIM / 4) / 256, 256, 0, stream>>>(hidden, value, gates, alphas, wcn, cw, outp);
}

// Round 3
// 538.533 us; speedup vs baseline: 1.3660x; 1.3660x over previous
//
#include <hip/hip_runtime.h>
#include <hip/hip_bf16.h>

// Problem constants
#define BDIM 4
#define SDIM 2048
#define MDIM 4
#define DDIM 2048
#define EDIM 1024
#define NTOK 8192           // B*S
#define NGEMM 10240         // D + M*D  (value cols + keys cols)
#define KDIM 1024           // E
#define EPS_GATE 1.1920929e-07f
#define EPS_CONV 1e-5f
#define RSQRT_D 0.022097086912079608f   // 1/sqrt(2048)

typedef __bf16 bf16x8 __attribute__((ext_vector_type(8)));
typedef float f32x4 __attribute__((ext_vector_type(4)));
typedef unsigned short ushort8 __attribute__((ext_vector_type(8)));

__constant__ int OFFS[8] = {0, 130003, 260024, 390051, 520094, 650145, 780202, 910271};

__device__ __forceinline__ float bf2f(unsigned short u) {
  union { unsigned int i; float f; } x; x.i = ((unsigned int)u) << 16; return x.f;
}
__device__ __forceinline__ unsigned short f2bf(float f) {
  __hip_bfloat16 h = __float2bfloat16(f);
  unsigned short u; __builtin_memcpy(&u, &h, 2); return u;
}

// ---------------- gather: emb_table rows -> bf16 emb [8192][1024] ------------
__global__ __launch_bounds__(256) void k_gather(const int* __restrict__ idx,
                                                const float* __restrict__ table,
                                                unsigned short* __restrict__ embb) {
  const int tok = blockIdx.x;
  const int tid = threadIdx.x;
  const int h = tid >> 5;            // 8 heads x 32 threads
  const int e = (tid & 31) * 4;      // 4 floats per thread
  const int row = idx[tok * 8 + h] + OFFS[h];
  const float4 v = *(const float4*)(table + (size_t)row * 128 + e);
  ushort4 st;
  st.x = f2bf(v.x); st.y = f2bf(v.y); st.z = f2bf(v.z); st.w = f2bf(v.w);
  *(ushort4*)(embb + (size_t)tok * 1024 + h * 128 + e) = st;
}

// ---------------- weight convert: [w_v ; w_k] fp32 -> bf16 [10240][1024] -----
__global__ __launch_bounds__(256) void k_cvtw(const float* __restrict__ wv,
                                              const float* __restrict__ wk,
                                              unsigned short* __restrict__ Wb) {
  const size_t i = ((size_t)blockIdx.x * 256 + threadIdx.x) * 4;
  const size_t NV = (size_t)DDIM * EDIM;  // 2097152
  float4 v;
  if (i < NV) v = *(const float4*)(wv + i);
  else        v = *(const float4*)(wk + (i - NV));
  ushort4 st;
  st.x = f2bf(v.x); st.y = f2bf(v.y); st.z = f2bf(v.z); st.w = f2bf(v.w);
  *(ushort4*)(Wb + i) = st;
}

// ---------------- GEMM: C[8192,10240] = emb[8192,1024] * W^T -----------------
// m97 structure: 128x128 tile, BK=64, global_load_lds(16B), mfma 16x16x32 bf16.
// Plain epilogue (round-1 style, no fusion): value cols -> bf16 Cv, key cols
// -> bf16 Ck. Score reductions live in their own memory-bound kernel.
#define GLDS(g, l) __builtin_amdgcn_global_load_lds(                        \
    (const __attribute__((address_space(1))) void*)(g),                    \
    (__attribute__((address_space(3))) void*)(l), 16, 0, 0)

__global__ __launch_bounds__(256) void k_gemm(const unsigned short* __restrict__ A,
                                              const unsigned short* __restrict__ Bw,
                                              unsigned short* __restrict__ Cv,  // [8192][2048] bf16
                                              unsigned short* __restrict__ Ck)  // [8192][8192] bf16
{
  __shared__ __align__(16) unsigned short lA[128 * 64];
  __shared__ __align__(16) unsigned short lB[128 * 64];
  const int tid = threadIdx.x;
  const int lane = tid & 63, wave = tid >> 6;
  const int row0 = blockIdx.y * 128;
  const int col0 = blockIdx.x * 128;
  const int wr = (wave >> 1) * 64, wc = (wave & 1) * 64;

  f32x4 acc[4][4] = {};

  for (int k0 = 0; k0 < KDIM; k0 += 64) {
#pragma unroll
    for (int it = 0; it < 4; ++it) {
      const int sg = wave * 4 + it;          // 16 segments of 1024B per tile
      const int chunk = sg * 64 + lane;      // 16B chunk index
      const int r = chunk >> 3;              // tile row (8 chunks per 128B row)
      const int c = (chunk & 7) * 8;         // bf16 col
      GLDS(A  + (size_t)(row0 + r) * KDIM + k0 + c, (char*)lA + sg * 1024);
      GLDS(Bw + (size_t)(col0 + r) * KDIM + k0 + c, (char*)lB + sg * 1024);
    }
    __syncthreads();
    const int lr = lane & 15;
#pragma unroll
    for (int kk = 0; kk < 2; ++kk) {
      const int lk = kk * 32 + (lane >> 4) * 8;
      bf16x8 af[4], bfr[4];
#pragma unroll
      for (int i = 0; i < 4; ++i)
        af[i] = *(const bf16x8*)(lA + (wr + i * 16 + lr) * 64 + lk);
#pragma unroll
      for (int i = 0; i < 4; ++i)
        bfr[i] = *(const bf16x8*)(lB + (wc + i * 16 + lr) * 64 + lk);
#pragma unroll
      for (int i = 0; i < 4; ++i)
#pragma unroll
        for (int j = 0; j < 4; ++j)
          acc[i][j] = __builtin_amdgcn_mfma_f32_16x16x32_bf16(af[i], bfr[j], acc[i][j], 0, 0, 0);
    }
    __syncthreads();
  }

  // epilogue: C/D layout col=lane&15, row=(lane>>4)*4+reg  [verified m89/m91]
  const int lcol = lane & 15;
  const int rbase = (lane >> 4) * 4;
#pragma unroll
  for (int i = 0; i < 4; ++i) {
#pragma unroll
    for (int j = 0; j < 4; ++j) {
      const int gr = row0 + wr + i * 16 + rbase;
      const int gc = col0 + wc + j * 16 + lcol;
      if (gc < DDIM) {
        unsigned short* p = Cv + (size_t)gr * DDIM + gc;
#pragma unroll
        for (int r = 0; r < 4; ++r) p[(size_t)r * DDIM] = f2bf(acc[i][j][r]);
      } else {
        unsigned short* p = Ck + (size_t)gr * 8192 + (gc - DDIM);
#pragma unroll
        for (int r = 0; r < 4; ++r) p[(size_t)r * 8192] = f2bf(acc[i][j][r]);
      }
    }
  }
}

// ---------------- score/gate: per (token, m) -> gate, alpha ------------------
__global__ __launch_bounds__(256) void k_score(const float* __restrict__ hidden,
                                               const unsigned short* __restrict__ valueb,
                                               const unsigned short* __restrict__ keysb,
                                               const float* __restrict__ norm_h,
                                               const float* __restrict__ norm_k,
                                               float* __restrict__ gates,
                                               float* __restrict__ alphas) {
  const int tok = blockIdx.x;
  const int tid = threadIdx.x, lane = tid & 63, m = tid >> 6;  // wave m handles branch m
  __shared__ float smv[4];

  // msv: mean(value^2) over D, cooperatively (wave m does quarter m)
  float pv = 0.f;
  {
    const ushort8 v8 = *(const ushort8*)(valueb + (size_t)tok * DDIM + (m * 64 + lane) * 8);
#pragma unroll
    for (int t = 0; t < 8; ++t) { const float f = bf2f(v8[t]); pv += f * f; }
  }

  const float4* hrow = (const float4*)(hidden + ((size_t)tok * 4 + m) * DDIM);
  const ushort4* krow = (const ushort4*)(keysb + (size_t)tok * 8192 + (size_t)m * DDIM);
  const float4* wkr = (const float4*)(norm_k + m * DDIM);
  const float4* whr = (const float4*)(norm_h + m * DDIM);
  float sk = 0.f, sh = 0.f, sd = 0.f;
#pragma unroll
  for (int i = 0; i < 8; ++i) {
    const int d4 = i * 64 + lane;
    const float4 h = hrow[d4];
    const float4 a = wkr[d4];
    const float4 b = whr[d4];
    const ushort4 ku = krow[d4];
    const float kx = bf2f(ku.x), ky = bf2f(ku.y), kz = bf2f(ku.z), kw = bf2f(ku.w);
    sk += kx * kx + ky * ky + kz * kz + kw * kw;
    sh += h.x * h.x + h.y * h.y + h.z * h.z + h.w * h.w;
    sd += kx * h.x * a.x * b.x + ky * h.y * a.y * b.y + kz * h.z * a.z * b.z + kw * h.w * a.w * b.w;
  }
#pragma unroll
  for (int off = 32; off > 0; off >>= 1) {
    pv += __shfl_down(pv, off);
    sk += __shfl_down(sk, off);
    sh += __shfl_down(sh, off);
    sd += __shfl_down(sd, off);
  }
  if (lane == 0) smv[m] = pv;
  __syncthreads();
  if (lane == 0) {
    const float msv = (smv[0] + smv[1] + smv[2] + smv[3]) * (1.f / 2048.f);
    const float msk = sk * (1.f / 2048.f) + EPS_GATE;
    const float msh = sh * (1.f / 2048.f) + EPS_GATE;
    const float score = sd * rsqrtf(msk) * rsqrtf(msh) * RSQRT_D;
    const float sgn = (score > 0.f) ? 1.f : ((score < 0.f) ? -1.f : 0.f);
    const float g = sqrtf(fmaxf(fabsf(score), 1e-6f)) * sgn;
    const float gate = 1.f / (1.f + expf(-g));
    gates[tok * 4 + m] = gate;
    alphas[tok * 4 + m] = gate * rsqrtf(gate * gate * msv + EPS_CONV);
  }
}

// ---------------- final: one thread owns (tok, d), loops m -------------------
// out[tok,m,d] = hidden + gate*v + silu(wcn * sum_j cw[:,3-j]*alpha_j*v(tok-3j))
__global__ __launch_bounds__(256) void k_final(const float* __restrict__ hidden,
                                               const unsigned short* __restrict__ valueb,
                                               const float* __restrict__ gates,
                                               const float* __restrict__ alphas,
                                               const float* __restrict__ wcn,
                                               const float* __restrict__ cw,   // [M*D][4]
                                               float* __restrict__ outp) {
  const long lin = (long)blockIdx.x * 256 + threadIdx.x;  // (tok, d4)
  const int d4 = (int)(lin & 511);
  const int tok = (int)(lin >> 9);
  const int s = tok & (SDIM - 1);
  const int d = d4 * 4;

  // conv taps: shared across all 4 branches
  float4 vj[4];
  {
    const ushort4 u = *(const ushort4*)(valueb + (size_t)tok * DDIM + d);
    vj[0] = make_float4(bf2f(u.x), bf2f(u.y), bf2f(u.z), bf2f(u.w));
  }
#pragma unroll
  for (int j = 1; j < 4; ++j) {
    if (s >= 3 * j) {
      const ushort4 u = *(const ushort4*)(valueb + (size_t)(tok - 3 * j) * DDIM + d);
      vj[j] = make_float4(bf2f(u.x), bf2f(u.y), bf2f(u.z), bf2f(u.w));
    } else vj[j] = make_float4(0.f, 0.f, 0.f, 0.f);
  }

#pragma unroll
  for (int m = 0; m < 4; ++m) {
    const float g = gates[tok * 4 + m];
    const float4 h4 = *(const float4*)(hidden + ((size_t)tok * 4 + m) * DDIM + d);
    const float4 wn = *(const float4*)(wcn + m * DDIM + d);
    float a[4];
#pragma unroll
    for (int j = 0; j < 4; ++j)
      a[j] = (s >= 3 * j) ? alphas[(tok - 3 * j) * 4 + m] : 0.f;
    float cwr[4][4];
#pragma unroll
    for (int i = 0; i < 4; ++i)
      *(float4*)cwr[i] = *(const float4*)(cw + (size_t)(m * DDIM + d + i) * 4);

    float cx = 0.f, cy = 0.f, cz = 0.f, cv = 0.f;
#pragma unroll
    for (int j = 0; j < 4; ++j) {
      const int t = 3 - j;
      const float aj = a[j];
      cx += cwr[0][t] * aj * vj[j].x;
      cy += cwr[1][t] * aj * vj[j].y;
      cz += cwr[2][t] * aj * vj[j].z;
      cv += cwr[3][t] * aj * vj[j].w;
    }
    cx *= wn.x; cy *= wn.y; cz *= wn.z; cv *= wn.w;
    cx = cx / (1.f + expf(-cx));
    cy = cy / (1.f + expf(-cy));
    cz = cz / (1.f + expf(-cz));
    cv = cv / (1.f + expf(-cv));

    float4 o;
    o.x = h4.x + g * vj[0].x + cx;
    o.y = h4.y + g * vj[0].y + cy;
    o.z = h4.z + g * vj[0].z + cz;
    o.w = h4.w + g * vj[0].w + cv;
    *(float4*)(outp + ((size_t)tok * 4 + m) * DDIM + d) = o;
  }
}

// ---------------- launcher ---------------------------------------------------
extern "C" void kernel_launch(void* const* d_in, const int* in_sizes, int n_in,
                              void* d_out, int out_size, void* d_ws, size_t ws_size,
                              hipStream_t stream) {
  const int*   hash_idx = (const int*)d_in[0];
  const float* hidden   = (const float*)d_in[1];
  const float* table    = (const float*)d_in[2];
  const float* w_v      = (const float*)d_in[3];
  const float* w_k      = (const float*)d_in[4];
  const float* norm_h   = (const float*)d_in[5];
  const float* norm_k   = (const float*)d_in[6];
  const float* wcn      = (const float*)d_in[7];
  const float* cw       = (const float*)d_in[8];
  float* outp = (float*)d_out;
  char* ws = (char*)d_ws;

  // workspace layout (bytes)
  unsigned short* embb  = (unsigned short*)(ws + 0);          // 8192*1024*2  = 16,777,216
  unsigned short* Wb    = (unsigned short*)(ws + 16777216);   // 10240*1024*2 = 20,971,520
  unsigned short* value = (unsigned short*)(ws + 37748736);   // 8192*2048*2  = 33,554,432
  unsigned short* keysb = (unsigned short*)(ws + 71303168);   // 8192*8192*2  = 134,217,728
  float*          gates = (float*)(ws + 205520896);           // 131,072
  float*          alphas= (float*)(ws + 205651968);           // 131,072  (end ~205.8 MB)

  k_gather<<<NTOK, 256, 0, stream>>>(hash_idx, table, embb);
  k_cvtw<<<10240, 256, 0, stream>>>(w_v, w_k, Wb);
  dim3 gg(NGEMM / 128, NTOK / 128);  // (80, 64)
  k_gemm<<<gg, 256, 0, stream>>>(embb, Wb, value, keysb);
  k_score<<<NTOK, 256, 0, stream>>>(hidden, value, keysb, norm_h, norm_k, gates, alphas);
  k_final<<<(NTOK * DDIM / 4) / 256, 256, 0, stream>>>(hidden, value, gates, alphas, wcn, cw, outp);
}